// Round 7
// baseline (83.446 us; speedup 1.0000x reference)
//
#include <hip/hip_runtime.h>
#include <hip/hip_bf16.h>
#include <hip/hip_fp16.h>

#define NN 4096
#define SDIM 64
#define HID 128
#define HEADS 4
#define FF 32
#define NSPLIT 32

typedef __attribute__((ext_vector_type(8))) short bfrag;      // 8 bf16 = 4 VGPR (MFMA A/B)
typedef __attribute__((ext_vector_type(4))) float f32x4;      // MFMA C/D
typedef __attribute__((ext_vector_type(4))) unsigned short us4;

__device__ inline short bfbits(float x) {
    __hip_bfloat16 h = __float2bfloat16(x);
    short s; __builtin_memcpy(&s, &h, 2); return s;
}

// ---------------- workspace layout (float units) ----------------
// hTf  : 0        (262144 f = 524288 bf16)  fragment-ordered h^T
// s1   : 262144   s2: 278528  E2: 294912  E2s: 311296
// cpos : 327680   cneg: 344064   (16384 each)
// abit : 376832   (524288 f = 2 MB bits)
// pout : 901120   (8388608 f-units = 16.8M fp16)   32 splits
// pden : 9289728  (524288)
// total 39.3 MB

// ============ K1: grid-partitioned prep (blocks 0..511, 8 rows each)
//                  + adjacency bit-pack (blocks 512..4607, 1 row each) ============
__global__ __launch_bounds__(256) void k_prep_pack(
        const float* __restrict__ state,
        const float* __restrict__ W1, const float* __restrict__ b1,
        const float* __restrict__ W2, const float* __restrict__ b2,
        const float* __restrict__ Wg, const float* __restrict__ ag,
        const int* __restrict__ adj,
        unsigned short* __restrict__ hTf,
        float* __restrict__ s1b, float* __restrict__ s2b,
        unsigned int* __restrict__ abit) {
    int tid = threadIdx.x;

    if (blockIdx.x >= 512) {
        // ---- pack branch: thread t packs 16 ints -> ushort ----
        int r = blockIdx.x - 512;
        const int4* ap = (const int4*)(adj + (size_t)r * NN + tid * 16);
        unsigned int b = 0;
#pragma unroll
        for (int i = 0; i < 4; i++) {
            int4 a = ap[i];
            b |= (unsigned int)(a.x != 0) << (i * 4 + 0);
            b |= (unsigned int)(a.y != 0) << (i * 4 + 1);
            b |= (unsigned int)(a.z != 0) << (i * 4 + 2);
            b |= (unsigned int)(a.w != 0) << (i * 4 + 3);
        }
        ((unsigned short*)abit)[r * 256 + tid] = (unsigned short)b;
        return;
    }

    // ---- prep branch: 8 rows/block, 256 threads ----
    __shared__ float srow[8][64];
    __shared__ float x1s[8][128];
    __shared__ float x2s[8][128];
    int r0 = blockIdx.x * 8;
    int c = tid & 127, g = tid >> 7;          // g = row-quad 0..1

    if (tid < 128)
        ((float4*)&srow[0][0])[tid] = ((const float4*)(state + (size_t)r0 * SDIM))[tid];
    __syncthreads();

    float acc[4];
    {   // x1 = relu(state@W1+b1)
        float bb = b1[c];
#pragma unroll
        for (int r = 0; r < 4; r++) acc[r] = bb;
#pragma unroll 8
        for (int k = 0; k < SDIM; k++) {
            float w = W1[k * HID + c];
#pragma unroll
            for (int r = 0; r < 4; r++) acc[r] += w * srow[g * 4 + r][k];
        }
#pragma unroll
        for (int r = 0; r < 4; r++) x1s[g * 4 + r][c] = fmaxf(acc[r], 0.f);
    }
    __syncthreads();
    {   // x2 = relu(x1@W2+b2)
        float bb = b2[c];
#pragma unroll
        for (int r = 0; r < 4; r++) acc[r] = bb;
#pragma unroll 8
        for (int k = 0; k < HID; k++) {
            float w = W2[k * HID + c];
#pragma unroll
            for (int r = 0; r < 4; r++) acc[r] += w * x1s[g * 4 + r][k];
        }
#pragma unroll
        for (int r = 0; r < 4; r++) x2s[g * 4 + r][c] = fmaxf(acc[r], 0.f);
    }
    __syncthreads();

    int hd = c >> 5, f = c & 31;
    float hacc[4];
#pragma unroll
    for (int r = 0; r < 4; r++) hacc[r] = 0.f;
#pragma unroll 8
    for (int k = 0; k < HID; k++) {
        float w = Wg[hd * (HID * FF) + k * FF + f];
#pragma unroll
        for (int r = 0; r < 4; r++) hacc[r] += w * x2s[g * 4 + r][k];
    }

    // h^T frag order: idx(hd,f,m) =
    //   ((hd*128 + (m>>5))*2 + (f>>4))*512 + (f&15)*32 + ((m&31)>>3)*8 + (m&7)
    {
        int bn = f >> 4, fr = f & 15;
        int m31 = (r0 & 31) + g * 4;
        us4 pk;
#pragma unroll
        for (int r = 0; r < 4; r++) pk[r] = (unsigned short)bfbits(hacc[r]);
        *(us4*)(hTf + (size_t)((hd * 128 + (r0 >> 5)) * 2 + bn) * 512
                + fr * 32 + (m31 >> 3) * 8 + (m31 & 7)) = pk;
    }

    float a1v = ag[hd * 64 + f];
    float a2v = ag[hd * 64 + 32 + f];
#pragma unroll
    for (int r = 0; r < 4; r++) {
        float p1 = hacc[r] * a1v;
        float p2 = hacc[r] * a2v;
#pragma unroll
        for (int s = 16; s >= 1; s >>= 1) {
            p1 += __shfl_xor(p1, s, 32);
            p2 += __shfl_xor(p2, s, 32);
        }
        if (f == 0) {
            s1b[hd * NN + r0 + g * 4 + r] = p1;
            s2b[hd * NN + r0 + g * 4 + r] = p2;
        }
    }
}

// ============ K2: per-head A2 + E2/E2s/cpos/cneg (1024 thr, 1 f32x4/thread) ============
__global__ __launch_bounds__(1024) void k_headprep(
        const float* __restrict__ s1b, const float* __restrict__ s2b,
        float* __restrict__ E2, float* __restrict__ E2s,
        float* __restrict__ cpos, float* __restrict__ cneg) {
    int hd = blockIdx.x;
    int tid = threadIdx.x;
    __shared__ float wmax[16];

    f32x4 v2 = *(const f32x4*)(s2b + hd * NN + tid * 4);
    float m = fmaxf(fmaxf(v2[0], v2[1]), fmaxf(v2[2], v2[3]));
#pragma unroll
    for (int s = 32; s >= 1; s >>= 1) m = fmaxf(m, __shfl_xor(m, s, 64));
    if ((tid & 63) == 0) wmax[tid >> 6] = m;
    __syncthreads();
    if (tid == 0) {
        float a = wmax[0];
#pragma unroll
        for (int i = 1; i < 16; i++) a = fmaxf(a, wmax[i]);
        wmax[0] = a;
    }
    __syncthreads();
    float A2 = wmax[0];

    f32x4 v1 = *(const f32x4*)(s1b + hd * NN + tid * 4);
    f32x4 e2, es, cp, cn;
#pragma unroll
    for (int i = 0; i < 4; i++) {
        e2[i] = __expf(v2[i] - A2);
        es[i] = __expf(0.2f * (v2[i] - A2));
        float u = v1[i] + A2;
        float C = fmaxf(u, 0.2f * u);
        cp[i] = __expf(u - C);
        cn[i] = __expf(0.2f * u - C);
    }
    *(f32x4*)(E2 + hd * NN + tid * 4) = e2;
    *(f32x4*)(E2s + hd * NN + tid * 4) = es;
    *(f32x4*)(cpos + hd * NN + tid * 4) = cp;
    *(f32x4*)(cneg + hd * NN + tid * 4) = cn;
}

// ============ K3: attention — max-form w, MFMA, 64-VGPR target ============
// w[n][m] = adj * max(cp[n]*E2[m], cn[n]*E2s[m])   (= adj * exp(lrelu(s1+s2)-C))
// block: 256 thr = 4 waves (wave = head); per block: 32 n-rows x 128 m-chunk
// grid: 128 row-tiles * 32 splits = 4096 blocks
__global__ __launch_bounds__(256, 8) void k_attn(
        const unsigned int* __restrict__ abit, const unsigned short* __restrict__ hTf,
        const float* __restrict__ E2, const float* __restrict__ E2s,
        const float* __restrict__ cposb, const float* __restrict__ cnegb,
        __half* __restrict__ pout, float* __restrict__ pden) {
    __shared__ unsigned int abits[32][5];   // 128-bit rows, padded stride 5

    int tid = threadIdx.x;
    int tile = blockIdx.x & 127;
    int split = blockIdx.x >> 7;
    int n0 = tile * 32, m0 = split * 128;

    if (tid < 128) {   // stage bitmask chunk: 32 rows x 4 words
        int r = tid >> 2, q = tid & 3;
        abits[r][q] = abit[(size_t)(n0 + r) * 128 + split * 4 + q];
    }
    __syncthreads();

    int hd = tid >> 6, lane = tid & 63;
    int fr = lane & 15, mo = lane >> 4;

    float cpv[2], cnv[2];
#pragma unroll
    for (int am = 0; am < 2; am++) {
        int n = n0 + am * 16 + fr;
        cpv[am] = cposb[hd * NN + n];
        cnv[am] = cnegb[hd * NN + n];
    }

    f32x4 acc[2][2];
#pragma unroll
    for (int am = 0; am < 2; am++)
#pragma unroll
        for (int bn = 0; bn < 2; bn++) acc[am][bn] = (f32x4){0.f, 0.f, 0.f, 0.f};
    float den[2] = {0.f, 0.f};

    const float* e2p = E2 + hd * NN + m0;
    const float* esp = E2s + hd * NN + m0;
    const unsigned short* hbase = hTf + (size_t)((hd * 128 + (m0 >> 5)) * 2) * 512 + fr * 32 + mo * 8;

#pragma unroll
    for (int ks = 0; ks < 4; ks++) {
        bfrag B0 = *(const bfrag*)(hbase + ks * 1024);
        bfrag B1 = *(const bfrag*)(hbase + ks * 1024 + 512);
        unsigned int bits8[2];
#pragma unroll
        for (int am = 0; am < 2; am++) bits8[am] = abits[am * 16 + fr][ks] >> (mo * 8);

        bfrag a8[2];
        float dtmp[2] = {0.f, 0.f};
#pragma unroll
        for (int half = 0; half < 2; half++) {
            int mb = ks * 32 + mo * 8 + half * 4;
            f32x4 e2v = *(const f32x4*)(e2p + mb);
            f32x4 esv = *(const f32x4*)(esp + mb);
#pragma unroll
            for (int am = 0; am < 2; am++) {
#pragma unroll
                for (int jj = 0; jj < 4; jj++) {
                    float w1 = cpv[am] * e2v[jj];
                    float w2 = cnv[am] * esv[jj];
                    float wv = fmaxf(w1, w2);
                    wv = ((bits8[am] >> (half * 4 + jj)) & 1u) ? wv : 0.f;
                    dtmp[am] += wv;
                    a8[am][half * 4 + jj] = bfbits(wv);
                }
            }
        }
#pragma unroll
        for (int am = 0; am < 2; am++) {
            den[am] += dtmp[am];
            acc[am][0] = __builtin_amdgcn_mfma_f32_16x16x32_bf16(a8[am], B0, acc[am][0], 0, 0, 0);
            acc[am][1] = __builtin_amdgcn_mfma_f32_16x16x32_bf16(a8[am], B1, acc[am][1], 0, 0, 0);
        }
    }

#pragma unroll
    for (int am = 0; am < 2; am++) {
        den[am] += __shfl_xor(den[am], 16);
        den[am] += __shfl_xor(den[am], 32);
    }

    __half* pob = pout + ((size_t)(split * 4 + hd) * NN + n0) * FF;
#pragma unroll
    for (int am = 0; am < 2; am++) {
#pragma unroll
        for (int bn = 0; bn < 2; bn++) {
            f32x4 cv = acc[am][bn];
#pragma unroll
            for (int r = 0; r < 4; r++)
                pob[(am * 16 + mo * 4 + r) * FF + bn * 16 + fr] = __float2half(cv[r]);
        }
        if (mo == 0)
            pden[(size_t)(split * 4 + hd) * NN + n0 + am * 16 + fr] = den[am];
    }
}

// ============ K4: fused reduce + policy + value (256 blocks x 512 thr) ============
__global__ __launch_bounds__(512) void k_redpolval(
        const __half* __restrict__ pout, const float* __restrict__ pden,
        const float* __restrict__ Wp1, const float* __restrict__ bp1,
        const float* __restrict__ Wp2, const float* __restrict__ bp2,
        const float* __restrict__ Wv1, const float* __restrict__ bv1,
        const float* __restrict__ Wv2, const float* __restrict__ bv2,
        float* __restrict__ out) {
    __shared__ float fr[16][128];
    __shared__ float hh[16][128];
    __shared__ float dens[16][4];
    int tid = threadIdx.x;
    int r0 = blockIdx.x * 16;

    // ---- phase 1: den[n][hd] = sum over 32 splits ----
    {
        int p = tid >> 3, sg = tid & 7;     // p = r*4+hd
        int r = p >> 2, hd = p & 3;
        float d = 0.f;
#pragma unroll
        for (int i = 0; i < 4; i++)
            d += pden[(size_t)((sg + i * 8) * 4 + hd) * NN + r0 + r];
#pragma unroll
        for (int s = 4; s >= 1; s >>= 1) d += __shfl_xor(d, s, 8);
        if (sg == 0) dens[r][hd] = d;
    }

    // ---- phase 2: feat = (sum of fp16 partials) / den ----
    int row = tid >> 5, c4 = (tid & 31) * 4;
    int hd2 = c4 >> 5;
    float o4[4] = {0.f, 0.f, 0.f, 0.f};
    const __half* pp = pout + ((size_t)hd2 * NN + r0 + row) * 32 + (c4 & 31);
#pragma unroll
    for (int s = 0; s < NSPLIT; s++) {
        float2 raw = *(const float2*)(pp + (size_t)s * 4 * NN * 32);
        __half2 ha = *(__half2*)&raw.x;
        __half2 hb = *(__half2*)&raw.y;
        float2 fa = __half22float2(ha), fb = __half22float2(hb);
        o4[0] += fa.x; o4[1] += fa.y; o4[2] += fb.x; o4[3] += fb.y;
    }
    __syncthreads();
    {
        float dn = fmaxf(dens[row][hd2], 1e-30f);
#pragma unroll
        for (int i = 0; i < 4; i++) fr[row][c4 + i] = o4[i] / dn;
    }
    __syncthreads();

    int c = tid & 127, g = tid >> 7;
    int c2 = tid & 31, r = tid >> 5;

    // ---- phase 3a: policy hidden ----
    {
        float acc[4];
        float bb = bp1[c];
#pragma unroll
        for (int q = 0; q < 4; q++) acc[q] = bb;
#pragma unroll 8
        for (int k = 0; k < HID; k++) {
            float w = Wp1[k * HID + c];
#pragma unroll
            for (int q = 0; q < 4; q++) acc[q] += w * fr[g * 4 + q][k];
        }
#pragma unroll
        for (int q = 0; q < 4; q++) hh[g * 4 + q][c] = fmaxf(acc[q], 0.f);
    }
    __syncthreads();
    {   // policy out + softmax
        float lacc = bp2[c2];
#pragma unroll 8
        for (int k = 0; k < HID; k++) lacc += hh[r][k] * Wp2[k * 32 + c2];
        float mx = lacc;
#pragma unroll
        for (int s = 16; s >= 1; s >>= 1) mx = fmaxf(mx, __shfl_xor(mx, s, 32));
        float e = __expf(lacc - mx);
        float sm = e;
#pragma unroll
        for (int s = 16; s >= 1; s >>= 1) sm += __shfl_xor(sm, s, 32);
        out[(size_t)(r0 + r) * 32 + c2] = e / sm;
    }
    __syncthreads();

    // ---- phase 3b: value hidden (reuse hh) ----
    {
        float acc[4];
        float bb = bv1[c];
#pragma unroll
        for (int q = 0; q < 4; q++) acc[q] = bb;
#pragma unroll 8
        for (int k = 0; k < HID; k++) {
            float w = Wv1[k * HID + c];
#pragma unroll
            for (int q = 0; q < 4; q++) acc[q] += w * fr[g * 4 + q][k];
        }
#pragma unroll
        for (int q = 0; q < 4; q++) hh[g * 4 + q][c] = fmaxf(acc[q], 0.f);
    }
    __syncthreads();
    {   // value out
        float p = 0.f;
#pragma unroll
        for (int j = 0; j < 4; j++) p += hh[r][c2 + j * 32] * Wv2[c2 + j * 32];
#pragma unroll
        for (int s = 16; s >= 1; s >>= 1) p += __shfl_xor(p, s, 32);
        if (c2 == 0) out[131072 + r0 + r] = p + bv2[0];
    }
}

extern "C" void kernel_launch(void* const* d_in, const int* in_sizes, int n_in,
                              void* d_out, int out_size, void* d_ws, size_t ws_size,
                              hipStream_t stream) {
    const float* state = (const float*)d_in[0];
    const int*   adj   = (const int*)d_in[1];
    const float* W1  = (const float*)d_in[2];
    const float* b1  = (const float*)d_in[3];
    const float* W2  = (const float*)d_in[4];
    const float* b2  = (const float*)d_in[5];
    const float* Wg  = (const float*)d_in[6];
    const float* ag  = (const float*)d_in[7];
    const float* Wp1 = (const float*)d_in[8];
    const float* bp1 = (const float*)d_in[9];
    const float* Wp2 = (const float*)d_in[10];
    const float* bp2 = (const float*)d_in[11];
    const float* Wv1 = (const float*)d_in[12];
    const float* bv1 = (const float*)d_in[13];
    const float* Wv2 = (const float*)d_in[14];
    const float* bv2 = (const float*)d_in[15];
    float* out = (float*)d_out;
    float* ws = (float*)d_ws;

    unsigned short* hTf = (unsigned short*)ws;          // 524288 bf16
    float* s1b  = ws + 262144;
    float* s2b  = ws + 278528;
    float* E2   = ws + 294912;
    float* E2s  = ws + 311296;
    float* cpos = ws + 327680;
    float* cneg = ws + 344064;
    unsigned int* abit = (unsigned int*)(ws + 376832);  // 2 MB
    __half* pout = (__half*)(ws + 901120);              // 16.8M fp16
    float* pden = ws + 9289728;

    hipLaunchKernelGGL(k_prep_pack, dim3(512 + NN), dim3(256), 0, stream,
                       state, W1, b1, W2, b2, Wg, ag, adj, hTf, s1b, s2b, abit);
    hipLaunchKernelGGL(k_headprep, dim3(HEADS), dim3(1024), 0, stream,
                       s1b, s2b, E2, E2s, cpos, cneg);
    hipLaunchKernelGGL(k_attn, dim3(128 * 32), dim3(256), 0, stream,
                       abit, hTf, E2, E2s, cpos, cneg, pout, pden);
    hipLaunchKernelGGL(k_redpolval, dim3(NN / 16), dim3(512), 0, stream,
                       pout, pden, Wp1, bp1, Wp2, bp2, Wv1, bv1, Wv2, bv2, out);
}

// Round 8
// 69.080 us; speedup vs baseline: 1.2080x; 1.2080x over previous
//
#include <hip/hip_runtime.h>
#include <hip/hip_bf16.h>
#include <hip/hip_fp16.h>

#define NN 4096
#define SDIM 64
#define HID 128
#define HEADS 4
#define FF 32
#define NSPLIT 16

typedef __attribute__((ext_vector_type(8))) short bfrag;      // 8 bf16 = 4 VGPR (MFMA A/B)
typedef __attribute__((ext_vector_type(4))) float f32x4;      // MFMA C/D
typedef __attribute__((ext_vector_type(4))) unsigned short us4;

__device__ inline short bfbits(float x) {
    __hip_bfloat16 h = __float2bfloat16(x);
    short s; __builtin_memcpy(&s, &h, 2); return s;
}

// ---------------- workspace layout (float units) ----------------
// hTf  : 0        (262144 f = 524288 bf16)  fragment-ordered h^T
// s1   : 262144   s2: 278528  E2: 294912  E2s: 311296
// cpos : 327680   cneg: 344064   (16384 each)
// abit : 376832   (524288 f = 2 MB bits)
// pout : 901120   (4194304 f-units = 8.4M fp16)   16 splits
// pden : 5095424  (262144)
// total 5357568 floats = 21.4 MB

// ============ K1: grid-partitioned prep (blocks 0..511, 8 rows each)
//                  + adjacency bit-pack (blocks 512..4607, 1 row each) ============
__global__ __launch_bounds__(256) void k_prep_pack(
        const float* __restrict__ state,
        const float* __restrict__ W1, const float* __restrict__ b1,
        const float* __restrict__ W2, const float* __restrict__ b2,
        const float* __restrict__ Wg, const float* __restrict__ ag,
        const int* __restrict__ adj,
        unsigned short* __restrict__ hTf,
        float* __restrict__ s1b, float* __restrict__ s2b,
        unsigned int* __restrict__ abit) {
    int tid = threadIdx.x;

    if (blockIdx.x >= 512) {
        // ---- pack branch: thread t packs 16 ints -> ushort ----
        int r = blockIdx.x - 512;
        const int4* ap = (const int4*)(adj + (size_t)r * NN + tid * 16);
        unsigned int b = 0;
#pragma unroll
        for (int i = 0; i < 4; i++) {
            int4 a = ap[i];
            b |= (unsigned int)(a.x != 0) << (i * 4 + 0);
            b |= (unsigned int)(a.y != 0) << (i * 4 + 1);
            b |= (unsigned int)(a.z != 0) << (i * 4 + 2);
            b |= (unsigned int)(a.w != 0) << (i * 4 + 3);
        }
        ((unsigned short*)abit)[r * 256 + tid] = (unsigned short)b;
        return;
    }

    // ---- prep branch: 8 rows/block, 256 threads ----
    __shared__ float srow[8][64];
    __shared__ float x1s[8][128];
    __shared__ float x2s[8][128];
    int r0 = blockIdx.x * 8;
    int c = tid & 127, g = tid >> 7;          // g = row-quad 0..1

    if (tid < 128)
        ((float4*)&srow[0][0])[tid] = ((const float4*)(state + (size_t)r0 * SDIM))[tid];
    __syncthreads();

    float acc[4];
    {   // x1 = relu(state@W1+b1)
        float bb = b1[c];
#pragma unroll
        for (int r = 0; r < 4; r++) acc[r] = bb;
#pragma unroll 8
        for (int k = 0; k < SDIM; k++) {
            float w = W1[k * HID + c];
#pragma unroll
            for (int r = 0; r < 4; r++) acc[r] += w * srow[g * 4 + r][k];
        }
#pragma unroll
        for (int r = 0; r < 4; r++) x1s[g * 4 + r][c] = fmaxf(acc[r], 0.f);
    }
    __syncthreads();
    {   // x2 = relu(x1@W2+b2)
        float bb = b2[c];
#pragma unroll
        for (int r = 0; r < 4; r++) acc[r] = bb;
#pragma unroll 8
        for (int k = 0; k < HID; k++) {
            float w = W2[k * HID + c];
#pragma unroll
            for (int r = 0; r < 4; r++) acc[r] += w * x1s[g * 4 + r][k];
        }
#pragma unroll
        for (int r = 0; r < 4; r++) x2s[g * 4 + r][c] = fmaxf(acc[r], 0.f);
    }
    __syncthreads();

    int hd = c >> 5, f = c & 31;
    float hacc[4];
#pragma unroll
    for (int r = 0; r < 4; r++) hacc[r] = 0.f;
#pragma unroll 8
    for (int k = 0; k < HID; k++) {
        float w = Wg[hd * (HID * FF) + k * FF + f];
#pragma unroll
        for (int r = 0; r < 4; r++) hacc[r] += w * x2s[g * 4 + r][k];
    }

    // h^T frag order: idx(hd,f,m) =
    //   ((hd*128 + (m>>5))*2 + (f>>4))*512 + (f&15)*32 + ((m&31)>>3)*8 + (m&7)
    {
        int bn = f >> 4, fr = f & 15;
        int m31 = (r0 & 31) + g * 4;
        us4 pk;
#pragma unroll
        for (int r = 0; r < 4; r++) pk[r] = (unsigned short)bfbits(hacc[r]);
        *(us4*)(hTf + (size_t)((hd * 128 + (r0 >> 5)) * 2 + bn) * 512
                + fr * 32 + (m31 >> 3) * 8 + (m31 & 7)) = pk;
    }

    float a1v = ag[hd * 64 + f];
    float a2v = ag[hd * 64 + 32 + f];
#pragma unroll
    for (int r = 0; r < 4; r++) {
        float p1 = hacc[r] * a1v;
        float p2 = hacc[r] * a2v;
#pragma unroll
        for (int s = 16; s >= 1; s >>= 1) {
            p1 += __shfl_xor(p1, s, 32);
            p2 += __shfl_xor(p2, s, 32);
        }
        if (f == 0) {
            s1b[hd * NN + r0 + g * 4 + r] = p1;
            s2b[hd * NN + r0 + g * 4 + r] = p2;
        }
    }
}

// ============ K2: per-head A2 + E2/E2s/cpos/cneg (1024 thr) ============
__global__ __launch_bounds__(1024) void k_headprep(
        const float* __restrict__ s1b, const float* __restrict__ s2b,
        float* __restrict__ E2, float* __restrict__ E2s,
        float* __restrict__ cpos, float* __restrict__ cneg) {
    int hd = blockIdx.x;
    int tid = threadIdx.x;
    __shared__ float wmax[16];

    f32x4 v2 = *(const f32x4*)(s2b + hd * NN + tid * 4);
    float m = fmaxf(fmaxf(v2[0], v2[1]), fmaxf(v2[2], v2[3]));
#pragma unroll
    for (int s = 32; s >= 1; s >>= 1) m = fmaxf(m, __shfl_xor(m, s, 64));
    if ((tid & 63) == 0) wmax[tid >> 6] = m;
    __syncthreads();
    if (tid == 0) {
        float a = wmax[0];
#pragma unroll
        for (int i = 1; i < 16; i++) a = fmaxf(a, wmax[i]);
        wmax[0] = a;
    }
    __syncthreads();
    float A2 = wmax[0];

    f32x4 v1 = *(const f32x4*)(s1b + hd * NN + tid * 4);
    f32x4 e2, es, cp, cn;
#pragma unroll
    for (int i = 0; i < 4; i++) {
        e2[i] = __expf(v2[i] - A2);
        es[i] = __expf(0.2f * (v2[i] - A2));
        float u = v1[i] + A2;
        float C = fmaxf(u, 0.2f * u);
        cp[i] = __expf(u - C);
        cn[i] = __expf(0.2f * u - C);
    }
    *(f32x4*)(E2 + hd * NN + tid * 4) = e2;
    *(f32x4*)(E2s + hd * NN + tid * 4) = es;
    *(f32x4*)(cpos + hd * NN + tid * 4) = cp;
    *(f32x4*)(cneg + hd * NN + tid * 4) = cn;
}

// ============ K3: attention — LDS-staged E2/E2s, MFMA w-GEMM + MFMA-den ============
// w[n][m] = adj * max(cp[n]*E2[m], cn[n]*E2s[m])
// block: 256 thr = 4 waves (wave = head); per block: 64 n-rows x 256 m-chunk
// grid: 64 row-tiles * 16 splits = 1024 blocks
__global__ __launch_bounds__(256, 4) void k_attn(
        const unsigned int* __restrict__ abit, const unsigned short* __restrict__ hTf,
        const float* __restrict__ E2, const float* __restrict__ E2s,
        const float* __restrict__ cposb, const float* __restrict__ cnegb,
        __half* __restrict__ pout, float* __restrict__ pden) {
    __shared__ unsigned int abits[64][9];   // 256-bit rows, padded stride 9
    __shared__ float e2l[4][256];           // E2 per head for this m-chunk
    __shared__ float esl[4][256];           // E2s

    int tid = threadIdx.x;
    int tile = blockIdx.x & 63;
    int split = blockIdx.x >> 6;
    int n0 = tile * 64, m0 = split * 256;

    {   // stage bitmask chunk: 64 rows x 8 words
        int r = tid >> 2, q = tid & 3;
        const unsigned int* src = abit + (size_t)(n0 + r) * 128 + split * 8 + q * 2;
        abits[r][q * 2 + 0] = src[0];
        abits[r][q * 2 + 1] = src[1];
    }
    {   // stage E2/E2s: 4 heads x 256 m each
#pragma unroll
        for (int i = 0; i < 4; i++) {
            int idx = tid + i * 256;
            int hd2 = idx >> 8, mm = idx & 255;
            e2l[hd2][mm] = E2[hd2 * NN + m0 + mm];
            esl[hd2][mm] = E2s[hd2 * NN + m0 + mm];
        }
    }
    __syncthreads();

    int hd = tid >> 6, lane = tid & 63;
    int fr = lane & 15, mo = lane >> 4;

    float cpv[4], cnv[4];
#pragma unroll
    for (int am = 0; am < 4; am++) {
        int n = n0 + am * 16 + fr;
        cpv[am] = cposb[hd * NN + n];
        cnv[am] = cnegb[hd * NN + n];
    }

    f32x4 acc[4][2];
    f32x4 accden[4];
#pragma unroll
    for (int am = 0; am < 4; am++) {
#pragma unroll
        for (int bn = 0; bn < 2; bn++) acc[am][bn] = (f32x4){0.f, 0.f, 0.f, 0.f};
        accden[am] = (f32x4){0.f, 0.f, 0.f, 0.f};
    }

    bfrag ones;
#pragma unroll
    for (int j = 0; j < 8; j++) ones[j] = (short)0x3F80;   // bf16 1.0

    const unsigned short* hbase = hTf + (size_t)((hd * 128 + (m0 >> 5)) * 2) * 512 + fr * 32 + mo * 8;
    const float* e2p = &e2l[hd][mo * 8];
    const float* esp = &esl[hd][mo * 8];

#pragma unroll 2
    for (int ks = 0; ks < 8; ks++) {
        bfrag B0 = *(const bfrag*)(hbase + ks * 1024);
        bfrag B1 = *(const bfrag*)(hbase + ks * 1024 + 512);
        f32x4 e2a = *(const f32x4*)(e2p + ks * 32);
        f32x4 e2b = *(const f32x4*)(e2p + ks * 32 + 4);
        f32x4 esa = *(const f32x4*)(esp + ks * 32);
        f32x4 esb = *(const f32x4*)(esp + ks * 32 + 4);

#pragma unroll
        for (int am = 0; am < 4; am++) {
            unsigned int bits = abits[am * 16 + fr][ks] >> (mo * 8);
            bfrag a8;
#pragma unroll
            for (int j = 0; j < 4; j++) {
                float wv = fmaxf(cpv[am] * e2a[j], cnv[am] * esa[j]);
                wv = ((bits >> j) & 1u) ? wv : 0.f;
                a8[j] = bfbits(wv);
            }
#pragma unroll
            for (int j = 0; j < 4; j++) {
                float wv = fmaxf(cpv[am] * e2b[j], cnv[am] * esb[j]);
                wv = ((bits >> (4 + j)) & 1u) ? wv : 0.f;
                a8[4 + j] = bfbits(wv);
            }
            acc[am][0] = __builtin_amdgcn_mfma_f32_16x16x32_bf16(a8, B0, acc[am][0], 0, 0, 0);
            acc[am][1] = __builtin_amdgcn_mfma_f32_16x16x32_bf16(a8, B1, acc[am][1], 0, 0, 0);
            accden[am] = __builtin_amdgcn_mfma_f32_16x16x32_bf16(a8, ones, accden[am], 0, 0, 0);
        }
    }

    __half* pob = pout + ((size_t)(split * 4 + hd) * NN + n0) * FF;
#pragma unroll
    for (int am = 0; am < 4; am++) {
#pragma unroll
        for (int bn = 0; bn < 2; bn++) {
            f32x4 cv = acc[am][bn];
#pragma unroll
            for (int r = 0; r < 4; r++)
                pob[(am * 16 + mo * 4 + r) * FF + bn * 16 + fr] = __float2half(cv[r]);
        }
        // accden D-layout: row = mo*4+r, col = fr (all cols equal rowsum)
        if (fr == 0) {
#pragma unroll
            for (int r = 0; r < 4; r++)
                pden[(size_t)(split * 4 + hd) * NN + n0 + am * 16 + mo * 4 + r] = accden[am][r];
        }
    }
}

// ============ K4: fused reduce + policy + value (256 blocks x 512 thr) ============
__global__ __launch_bounds__(512) void k_redpolval(
        const __half* __restrict__ pout, const float* __restrict__ pden,
        const float* __restrict__ Wp1, const float* __restrict__ bp1,
        const float* __restrict__ Wp2, const float* __restrict__ bp2,
        const float* __restrict__ Wv1, const float* __restrict__ bv1,
        const float* __restrict__ Wv2, const float* __restrict__ bv2,
        float* __restrict__ out) {
    __shared__ float fr[16][128];
    __shared__ float hh[16][128];
    __shared__ float dens[16][4];
    int tid = threadIdx.x;
    int r0 = blockIdx.x * 16;

    // ---- phase 1: den[n][hd] = sum over 16 splits ----
    {
        int p = tid >> 3, sg = tid & 7;     // p = r*4+hd
        int r = p >> 2, hd = p & 3;
        float d = 0.f;
#pragma unroll
        for (int i = 0; i < NSPLIT / 8; i++)
            d += pden[(size_t)((sg + i * 8) * 4 + hd) * NN + r0 + r];
#pragma unroll
        for (int s = 4; s >= 1; s >>= 1) d += __shfl_xor(d, s, 8);
        if (sg == 0) dens[r][hd] = d;
    }

    // ---- phase 2: feat = (sum of fp16 partials) / den ----
    int row = tid >> 5, c4 = (tid & 31) * 4;
    int hd2 = c4 >> 5;
    float o4[4] = {0.f, 0.f, 0.f, 0.f};
    const __half* pp = pout + ((size_t)hd2 * NN + r0 + row) * 32 + (c4 & 31);
#pragma unroll
    for (int s = 0; s < NSPLIT; s++) {
        float2 raw = *(const float2*)(pp + (size_t)s * 4 * NN * 32);
        __half2 ha = *(__half2*)&raw.x;
        __half2 hb = *(__half2*)&raw.y;
        float2 fa = __half22float2(ha), fb = __half22float2(hb);
        o4[0] += fa.x; o4[1] += fa.y; o4[2] += fb.x; o4[3] += fb.y;
    }
    __syncthreads();
    {
        float dn = fmaxf(dens[row][hd2], 1e-30f);
#pragma unroll
        for (int i = 0; i < 4; i++) fr[row][c4 + i] = o4[i] / dn;
    }
    __syncthreads();

    int c = tid & 127, g = tid >> 7;
    int c2 = tid & 31, r = tid >> 5;

    // ---- phase 3a: policy hidden ----
    {
        float acc[4];
        float bb = bp1[c];
#pragma unroll
        for (int q = 0; q < 4; q++) acc[q] = bb;
#pragma unroll 8
        for (int k = 0; k < HID; k++) {
            float w = Wp1[k * HID + c];
#pragma unroll
            for (int q = 0; q < 4; q++) acc[q] += w * fr[g * 4 + q][k];
        }
#pragma unroll
        for (int q = 0; q < 4; q++) hh[g * 4 + q][c] = fmaxf(acc[q], 0.f);
    }
    __syncthreads();
    {   // policy out + softmax
        float lacc = bp2[c2];
#pragma unroll 8
        for (int k = 0; k < HID; k++) lacc += hh[r][k] * Wp2[k * 32 + c2];
        float mx = lacc;
#pragma unroll
        for (int s = 16; s >= 1; s >>= 1) mx = fmaxf(mx, __shfl_xor(mx, s, 32));
        float e = __expf(lacc - mx);
        float sm = e;
#pragma unroll
        for (int s = 16; s >= 1; s >>= 1) sm += __shfl_xor(sm, s, 32);
        out[(size_t)(r0 + r) * 32 + c2] = e / sm;
    }
    __syncthreads();

    // ---- phase 3b: value hidden (reuse hh) ----
    {
        float acc[4];
        float bb = bv1[c];
#pragma unroll
        for (int q = 0; q < 4; q++) acc[q] = bb;
#pragma unroll 8
        for (int k = 0; k < HID; k++) {
            float w = Wv1[k * HID + c];
#pragma unroll
            for (int q = 0; q < 4; q++) acc[q] += w * fr[g * 4 + q][k];
        }
#pragma unroll
        for (int q = 0; q < 4; q++) hh[g * 4 + q][c] = fmaxf(acc[q], 0.f);
    }
    __syncthreads();
    {   // value out
        float p = 0.f;
#pragma unroll
        for (int j = 0; j < 4; j++) p += hh[r][c2 + j * 32] * Wv2[c2 + j * 32];
#pragma unroll
        for (int s = 16; s >= 1; s >>= 1) p += __shfl_xor(p, s, 32);
        if (c2 == 0) out[131072 + r0 + r] = p + bv2[0];
    }
}

extern "C" void kernel_launch(void* const* d_in, const int* in_sizes, int n_in,
                              void* d_out, int out_size, void* d_ws, size_t ws_size,
                              hipStream_t stream) {
    const float* state = (const float*)d_in[0];
    const int*   adj   = (const int*)d_in[1];
    const float* W1  = (const float*)d_in[2];
    const float* b1  = (const float*)d_in[3];
    const float* W2  = (const float*)d_in[4];
    const float* b2  = (const float*)d_in[5];
    const float* Wg  = (const float*)d_in[6];
    const float* ag  = (const float*)d_in[7];
    const float* Wp1 = (const float*)d_in[8];
    const float* bp1 = (const float*)d_in[9];
    const float* Wp2 = (const float*)d_in[10];
    const float* bp2 = (const float*)d_in[11];
    const float* Wv1 = (const float*)d_in[12];
    const float* bv1 = (const float*)d_in[13];
    const float* Wv2 = (const float*)d_in[14];
    const float* bv2 = (const float*)d_in[15];
    float* out = (float*)d_out;
    float* ws = (float*)d_ws;

    unsigned short* hTf = (unsigned short*)ws;          // 524288 bf16
    float* s1b  = ws + 262144;
    float* s2b  = ws + 278528;
    float* E2   = ws + 294912;
    float* E2s  = ws + 311296;
    float* cpos = ws + 327680;
    float* cneg = ws + 344064;
    unsigned int* abit = (unsigned int*)(ws + 376832);  // 2 MB
    __half* pout = (__half*)(ws + 901120);              // 8.4M fp16
    float* pden = ws + 5095424;

    hipLaunchKernelGGL(k_prep_pack, dim3(512 + NN), dim3(256), 0, stream,
                       state, W1, b1, W2, b2, Wg, ag, adj, hTf, s1b, s2b, abit);
    hipLaunchKernelGGL(k_headprep, dim3(HEADS), dim3(1024), 0, stream,
                       s1b, s2b, E2, E2s, cpos, cneg);
    hipLaunchKernelGGL(k_attn, dim3(64 * NSPLIT), dim3(256), 0, stream,
                       abit, hTf, E2, E2s, cpos, cneg, pout, pden);
    hipLaunchKernelGGL(k_redpolval, dim3(NN / 16), dim3(512), 0, stream,
                       pout, pden, Wp1, bp1, Wp2, bp2, Wv1, bv1, Wv2, bv2, out);
}

// Round 9
// 68.751 us; speedup vs baseline: 1.2137x; 1.0048x over previous
//
#include <hip/hip_runtime.h>
#include <hip/hip_bf16.h>
#include <hip/hip_fp16.h>

#define NN 4096
#define SDIM 64
#define HID 128
#define HEADS 4
#define FF 32
#define NSPLIT 8

typedef __attribute__((ext_vector_type(8))) _Float16 h8;      // MFMA f16 A/B frag
typedef __attribute__((ext_vector_type(2))) _Float16 h2;
typedef __attribute__((ext_vector_type(4))) float f32x4;      // MFMA C/D
typedef __attribute__((ext_vector_type(4))) unsigned short us4;

__device__ inline h2 h2max(h2 a, h2 b) {
    h2 r; r[0] = a[0] > b[0] ? a[0] : b[0]; r[1] = a[1] > b[1] ? a[1] : b[1]; return r;
}

// ---------------- workspace layout (float units) ----------------
// hTf  : 0        (262144 f = 524288 fp16)  fragment-ordered h^T
// s1   : 262144   s2: 278528   (16384 each)
// E2h  : 294912   (8192 f = 16384 fp16)
// E2sh : 303104   (8192)
// cpos : 311296   cneg: 327680  (16384 each, f32)
// abit : 344064   (524288 f = 2 MB bits)
// pout : 868352   (2097152 f = 4.2M fp16)   8 splits
// pden : 2965504  (131072)
// total 3096576 floats = 12.4 MB

// ============ K1: grid-partitioned prep (blocks 0..511, 8 rows each)
//                  + adjacency bit-pack (blocks 512..4607, 1 row each) ============
__global__ __launch_bounds__(256) void k_prep_pack(
        const float* __restrict__ state,
        const float* __restrict__ W1, const float* __restrict__ b1,
        const float* __restrict__ W2, const float* __restrict__ b2,
        const float* __restrict__ Wg, const float* __restrict__ ag,
        const int* __restrict__ adj,
        unsigned short* __restrict__ hTf,
        float* __restrict__ s1b, float* __restrict__ s2b,
        unsigned int* __restrict__ abit) {
    int tid = threadIdx.x;

    if (blockIdx.x >= 512) {
        // ---- pack branch: thread t packs 16 ints -> ushort ----
        int r = blockIdx.x - 512;
        const int4* ap = (const int4*)(adj + (size_t)r * NN + tid * 16);
        unsigned int b = 0;
#pragma unroll
        for (int i = 0; i < 4; i++) {
            int4 a = ap[i];
            b |= (unsigned int)(a.x != 0) << (i * 4 + 0);
            b |= (unsigned int)(a.y != 0) << (i * 4 + 1);
            b |= (unsigned int)(a.z != 0) << (i * 4 + 2);
            b |= (unsigned int)(a.w != 0) << (i * 4 + 3);
        }
        ((unsigned short*)abit)[r * 256 + tid] = (unsigned short)b;
        return;
    }

    // ---- prep branch: 8 rows/block, 256 threads ----
    __shared__ float srow[8][64];
    __shared__ float x1s[8][128];
    __shared__ float x2s[8][128];
    int r0 = blockIdx.x * 8;
    int c = tid & 127, g = tid >> 7;          // g = row-quad 0..1

    if (tid < 128)
        ((float4*)&srow[0][0])[tid] = ((const float4*)(state + (size_t)r0 * SDIM))[tid];
    __syncthreads();

    float acc[4];
    {   // x1 = relu(state@W1+b1)
        float bb = b1[c];
#pragma unroll
        for (int r = 0; r < 4; r++) acc[r] = bb;
#pragma unroll 8
        for (int k = 0; k < SDIM; k++) {
            float w = W1[k * HID + c];
#pragma unroll
            for (int r = 0; r < 4; r++) acc[r] += w * srow[g * 4 + r][k];
        }
#pragma unroll
        for (int r = 0; r < 4; r++) x1s[g * 4 + r][c] = fmaxf(acc[r], 0.f);
    }
    __syncthreads();
    {   // x2 = relu(x1@W2+b2)
        float bb = b2[c];
#pragma unroll
        for (int r = 0; r < 4; r++) acc[r] = bb;
#pragma unroll 8
        for (int k = 0; k < HID; k++) {
            float w = W2[k * HID + c];
#pragma unroll
            for (int r = 0; r < 4; r++) acc[r] += w * x1s[g * 4 + r][k];
        }
#pragma unroll
        for (int r = 0; r < 4; r++) x2s[g * 4 + r][c] = fmaxf(acc[r], 0.f);
    }
    __syncthreads();

    int hd = c >> 5, f = c & 31;
    float hacc[4];
#pragma unroll
    for (int r = 0; r < 4; r++) hacc[r] = 0.f;
#pragma unroll 8
    for (int k = 0; k < HID; k++) {
        float w = Wg[hd * (HID * FF) + k * FF + f];
#pragma unroll
        for (int r = 0; r < 4; r++) hacc[r] += w * x2s[g * 4 + r][k];
    }

    // h^T frag order (fp16 now): idx(hd,f,m) =
    //   ((hd*128 + (m>>5))*2 + (f>>4))*512 + (f&15)*32 + ((m&31)>>3)*8 + (m&7)
    {
        int bn = f >> 4, fr = f & 15;
        int m31 = (r0 & 31) + g * 4;
        us4 pk;
#pragma unroll
        for (int r = 0; r < 4; r++) pk[r] = __half_as_ushort(__float2half(hacc[r]));
        *(us4*)(hTf + (size_t)((hd * 128 + (r0 >> 5)) * 2 + bn) * 512
                + fr * 32 + (m31 >> 3) * 8 + (m31 & 7)) = pk;
    }

    float a1v = ag[hd * 64 + f];
    float a2v = ag[hd * 64 + 32 + f];
#pragma unroll
    for (int r = 0; r < 4; r++) {
        float p1 = hacc[r] * a1v;
        float p2 = hacc[r] * a2v;
#pragma unroll
        for (int s = 16; s >= 1; s >>= 1) {
            p1 += __shfl_xor(p1, s, 32);
            p2 += __shfl_xor(p2, s, 32);
        }
        if (f == 0) {
            s1b[hd * NN + r0 + g * 4 + r] = p1;
            s2b[hd * NN + r0 + g * 4 + r] = p2;
        }
    }
}

// ============ K2: per-head A2 + E2h/E2sh(fp16) + cpos/cneg(f32) ============
__global__ __launch_bounds__(1024) void k_headprep(
        const float* __restrict__ s1b, const float* __restrict__ s2b,
        unsigned short* __restrict__ E2h, unsigned short* __restrict__ E2sh,
        float* __restrict__ cpos, float* __restrict__ cneg) {
    int hd = blockIdx.x;
    int tid = threadIdx.x;
    __shared__ float wmax[16];

    f32x4 v2 = *(const f32x4*)(s2b + hd * NN + tid * 4);
    float m = fmaxf(fmaxf(v2[0], v2[1]), fmaxf(v2[2], v2[3]));
#pragma unroll
    for (int s = 32; s >= 1; s >>= 1) m = fmaxf(m, __shfl_xor(m, s, 64));
    if ((tid & 63) == 0) wmax[tid >> 6] = m;
    __syncthreads();
    if (tid == 0) {
        float a = wmax[0];
#pragma unroll
        for (int i = 1; i < 16; i++) a = fmaxf(a, wmax[i]);
        wmax[0] = a;
    }
    __syncthreads();
    float A2 = wmax[0];

    f32x4 v1 = *(const f32x4*)(s1b + hd * NN + tid * 4);
    us4 e2p, esp;
    f32x4 cp, cn;
#pragma unroll
    for (int i = 0; i < 4; i++) {
        e2p[i] = __half_as_ushort(__float2half(__expf(v2[i] - A2)));
        esp[i] = __half_as_ushort(__float2half(__expf(0.2f * (v2[i] - A2))));
        float u = v1[i] + A2;
        float C = fmaxf(u, 0.2f * u);
        cp[i] = __expf(u - C);
        cn[i] = __expf(0.2f * u - C);
    }
    *(us4*)(E2h + hd * NN + tid * 4) = e2p;
    *(us4*)(E2sh + hd * NN + tid * 4) = esp;
    *(f32x4*)(cpos + hd * NN + tid * 4) = cp;
    *(f32x4*)(cneg + hd * NN + tid * 4) = cn;
}

// ============ K3: attention — fp16 packed w-build, f16 MFMA + MFMA-den ============
// w[n][m] = adj * max(cp[n]*E2[m], cn[n]*E2s[m])
// block: 256 thr = 4 waves (wave = head); per block: 32 n-rows x 512 m-chunk
// grid: 128 row-tiles * 8 splits = 1024 blocks
__global__ __launch_bounds__(256, 4) void k_attn(
        const unsigned int* __restrict__ abit, const unsigned short* __restrict__ hTf,
        const unsigned short* __restrict__ E2h, const unsigned short* __restrict__ E2sh,
        const float* __restrict__ cposb, const float* __restrict__ cnegb,
        __half* __restrict__ pout, float* __restrict__ pden) {
    __shared__ unsigned int abits[32][17];      // 512-bit rows, padded stride 17
    __shared__ unsigned short e2l[4][512];      // fp16 E2 per head
    __shared__ unsigned short esl[4][512];      // fp16 E2s

    int tid = threadIdx.x;
    int tile = blockIdx.x & 127;
    int split = blockIdx.x >> 7;
    int n0 = tile * 32, m0 = split * 512;

    {   // stage bitmask chunk: 32 rows x 16 words (2 words/thread)
        int r = tid >> 3, qq = (tid & 7) * 2;
        const unsigned int* src = abit + (size_t)(n0 + r) * 128 + split * 16 + qq;
        abits[r][qq] = src[0];
        abits[r][qq + 1] = src[1];
    }
    {   // stage E2h/E2sh: 4 heads x 512 halves each (8 halves/thread)
        int idx = tid * 8;
        int hd2 = idx >> 9, mm = idx & 511;
        *(uint4*)&e2l[hd2][mm] = *(const uint4*)(E2h + hd2 * NN + m0 + mm);
        *(uint4*)&esl[hd2][mm] = *(const uint4*)(E2sh + hd2 * NN + m0 + mm);
    }
    __syncthreads();

    int hd = tid >> 6, lane = tid & 63;
    int fr = lane & 15, mo = lane >> 4;

    h2 cph[2], cnh[2];
#pragma unroll
    for (int am = 0; am < 2; am++) {
        int n = n0 + am * 16 + fr;
        _Float16 t1 = (_Float16)cposb[hd * NN + n];
        _Float16 t2 = (_Float16)cnegb[hd * NN + n];
        cph[am][0] = t1; cph[am][1] = t1;
        cnh[am][0] = t2; cnh[am][1] = t2;
    }

    f32x4 acc[2][2];
    f32x4 accden[2];
#pragma unroll
    for (int am = 0; am < 2; am++) {
#pragma unroll
        for (int bn = 0; bn < 2; bn++) acc[am][bn] = (f32x4){0.f, 0.f, 0.f, 0.f};
        accden[am] = (f32x4){0.f, 0.f, 0.f, 0.f};
    }

    h8 ones;
#pragma unroll
    for (int j = 0; j < 8; j++) ones[j] = (_Float16)1.0f;

    const unsigned short* hbase = hTf + (size_t)((hd * 128 + (m0 >> 5)) * 2) * 512 + fr * 32 + mo * 8;

#pragma unroll 4
    for (int ks = 0; ks < 16; ks++) {
        h8 B0 = *(const h8*)(hbase + ks * 1024);
        h8 B1 = *(const h8*)(hbase + ks * 1024 + 512);
        uint4 e2v = *(const uint4*)(&e2l[hd][ks * 32 + mo * 8]);
        uint4 esv = *(const uint4*)(&esl[hd][ks * 32 + mo * 8]);

#pragma unroll
        for (int am = 0; am < 2; am++) {
            unsigned int bits = abits[am * 16 + fr][ks] >> (mo * 8);
            union { unsigned int u[4]; h8 v; } A;
#pragma unroll
            for (int p = 0; p < 4; p++) {
                unsigned int eu = (&e2v.x)[p], su = (&esv.x)[p];
                h2 e2h, esh;
                __builtin_memcpy(&e2h, &eu, 4);
                __builtin_memcpy(&esh, &su, 4);
                h2 w2 = h2max(cph[am] * e2h, cnh[am] * esh);
                unsigned int wm;
                __builtin_memcpy(&wm, &w2, 4);
                unsigned int b0 = (bits >> (2 * p)) & 1u;
                unsigned int b1 = (bits >> (2 * p + 1)) & 1u;
                wm &= ((0u - b0) & 0xFFFFu) | ((0u - b1) << 16);
                A.u[p] = wm;
            }
            acc[am][0] = __builtin_amdgcn_mfma_f32_16x16x32_f16(A.v, B0, acc[am][0], 0, 0, 0);
            acc[am][1] = __builtin_amdgcn_mfma_f32_16x16x32_f16(A.v, B1, acc[am][1], 0, 0, 0);
            accden[am] = __builtin_amdgcn_mfma_f32_16x16x32_f16(A.v, ones, accden[am], 0, 0, 0);
        }
    }

    __half* pob = pout + ((size_t)(split * 4 + hd) * NN + n0) * FF;
#pragma unroll
    for (int am = 0; am < 2; am++) {
#pragma unroll
        for (int bn = 0; bn < 2; bn++) {
            f32x4 cv = acc[am][bn];
#pragma unroll
            for (int r = 0; r < 4; r++)
                pob[(am * 16 + mo * 4 + r) * FF + bn * 16 + fr] = __float2half(cv[r]);
        }
        // accden D-layout: row = mo*4+r, col = fr (all cols equal rowsum)
        if (fr == 0) {
#pragma unroll
            for (int r = 0; r < 4; r++)
                pden[(size_t)(split * 4 + hd) * NN + n0 + am * 16 + mo * 4 + r] = accden[am][r];
        }
    }
}

// ============ K4: fused reduce + policy + value (256 blocks x 512 thr) ============
__global__ __launch_bounds__(512) void k_redpolval(
        const __half* __restrict__ pout, const float* __restrict__ pden,
        const float* __restrict__ Wp1, const float* __restrict__ bp1,
        const float* __restrict__ Wp2, const float* __restrict__ bp2,
        const float* __restrict__ Wv1, const float* __restrict__ bv1,
        const float* __restrict__ Wv2, const float* __restrict__ bv2,
        float* __restrict__ out) {
    __shared__ float fr[16][128];
    __shared__ float hh[16][128];
    __shared__ float dens[16][4];
    int tid = threadIdx.x;
    int r0 = blockIdx.x * 16;

    // ---- phase 1: den[n][hd] = sum over 8 splits ----
    {
        int p = tid >> 3, sg = tid & 7;     // p = r*4+hd
        int r = p >> 2, hd = p & 3;
        float d = pden[(size_t)(sg * 4 + hd) * NN + r0 + r];
#pragma unroll
        for (int s = 4; s >= 1; s >>= 1) d += __shfl_xor(d, s, 8);
        if (sg == 0) dens[r][hd] = d;
    }

    // ---- phase 2: feat = (sum of fp16 partials) / den ----
    int row = tid >> 5, c4 = (tid & 31) * 4;
    int hd2 = c4 >> 5;
    float o4[4] = {0.f, 0.f, 0.f, 0.f};
    const __half* pp = pout + ((size_t)hd2 * NN + r0 + row) * 32 + (c4 & 31);
#pragma unroll
    for (int s = 0; s < NSPLIT; s++) {
        float2 raw = *(const float2*)(pp + (size_t)s * 4 * NN * 32);
        __half2 ha = *(__half2*)&raw.x;
        __half2 hb = *(__half2*)&raw.y;
        float2 fa = __half22float2(ha), fb = __half22float2(hb);
        o4[0] += fa.x; o4[1] += fa.y; o4[2] += fb.x; o4[3] += fb.y;
    }
    __syncthreads();
    {
        float dn = fmaxf(dens[row][hd2], 1e-30f);
#pragma unroll
        for (int i = 0; i < 4; i++) fr[row][c4 + i] = o4[i] / dn;
    }
    __syncthreads();

    int c = tid & 127, g = tid >> 7;
    int c2 = tid & 31, r = tid >> 5;

    // ---- phase 3a: policy hidden ----
    {
        float acc[4];
        float bb = bp1[c];
#pragma unroll
        for (int q = 0; q < 4; q++) acc[q] = bb;
#pragma unroll 8
        for (int k = 0; k < HID; k++) {
            float w = Wp1[k * HID + c];
#pragma unroll
            for (int q = 0; q < 4; q++) acc[q] += w * fr[g * 4 + q][k];
        }
#pragma unroll
        for (int q = 0; q < 4; q++) hh[g * 4 + q][c] = fmaxf(acc[q], 0.f);
    }
    __syncthreads();
    {   // policy out + softmax
        float lacc = bp2[c2];
#pragma unroll 8
        for (int k = 0; k < HID; k++) lacc += hh[r][k] * Wp2[k * 32 + c2];
        float mx = lacc;
#pragma unroll
        for (int s = 16; s >= 1; s >>= 1) mx = fmaxf(mx, __shfl_xor(mx, s, 32));
        float e = __expf(lacc - mx);
        float sm = e;
#pragma unroll
        for (int s = 16; s >= 1; s >>= 1) sm += __shfl_xor(sm, s, 32);
        out[(size_t)(r0 + r) * 32 + c2] = e / sm;
    }
    __syncthreads();

    // ---- phase 3b: value hidden (reuse hh) ----
    {
        float acc[4];
        float bb = bv1[c];
#pragma unroll
        for (int q = 0; q < 4; q++) acc[q] = bb;
#pragma unroll 8
        for (int k = 0; k < HID; k++) {
            float w = Wv1[k * HID + c];
#pragma unroll
            for (int q = 0; q < 4; q++) acc[q] += w * fr[g * 4 + q][k];
        }
#pragma unroll
        for (int q = 0; q < 4; q++) hh[g * 4 + q][c] = fmaxf(acc[q], 0.f);
    }
    __syncthreads();
    {   // value out
        float p = 0.f;
#pragma unroll
        for (int j = 0; j < 4; j++) p += hh[r][c2 + j * 32] * Wv2[c2 + j * 32];
#pragma unroll
        for (int s = 16; s >= 1; s >>= 1) p += __shfl_xor(p, s, 32);
        if (c2 == 0) out[131072 + r0 + r] = p + bv2[0];
    }
}

extern "C" void kernel_launch(void* const* d_in, const int* in_sizes, int n_in,
                              void* d_out, int out_size, void* d_ws, size_t ws_size,
                              hipStream_t stream) {
    const float* state = (const float*)d_in[0];
    const int*   adj   = (const int*)d_in[1];
    const float* W1  = (const float*)d_in[2];
    const float* b1  = (const float*)d_in[3];
    const float* W2  = (const float*)d_in[4];
    const float* b2  = (const float*)d_in[5];
    const float* Wg  = (const float*)d_in[6];
    const float* ag  = (const float*)d_in[7];
    const float* Wp1 = (const float*)d_in[8];
    const float* bp1 = (const float*)d_in[9];
    const float* Wp2 = (const float*)d_in[10];
    const float* bp2 = (const float*)d_in[11];
    const float* Wv1 = (const float*)d_in[12];
    const float* bv1 = (const float*)d_in[13];
    const float* Wv2 = (const float*)d_in[14];
    const float* bv2 = (const float*)d_in[15];
    float* out = (float*)d_out;
    float* ws = (float*)d_ws;

    unsigned short* hTf = (unsigned short*)ws;            // 524288 fp16
    float* s1b  = ws + 262144;
    float* s2b  = ws + 278528;
    unsigned short* E2h  = (unsigned short*)(ws + 294912);
    unsigned short* E2sh = (unsigned short*)(ws + 303104);
    float* cpos = ws + 311296;
    float* cneg = ws + 327680;
    unsigned int* abit = (unsigned int*)(ws + 344064);    // 2 MB
    __half* pout = (__half*)(ws + 868352);                // 4.2M fp16
    float* pden = ws + 2965504;

    hipLaunchKernelGGL(k_prep_pack, dim3(512 + NN), dim3(256), 0, stream,
                       state, W1, b1, W2, b2, Wg, ag, adj, hTf, s1b, s2b, abit);
    hipLaunchKernelGGL(k_headprep, dim3(HEADS), dim3(1024), 0, stream,
                       s1b, s2b, E2h, E2sh, cpos, cneg);
    hipLaunchKernelGGL(k_attn, dim3(128 * NSPLIT), dim3(256), 0, stream,
                       abit, hTf, E2h, E2sh, cpos, cneg, pout, pden);
    hipLaunchKernelGGL(k_redpolval, dim3(NN / 16), dim3(512), 0, stream,
                       pout, pden, Wp1, bp1, Wp2, bp2, Wv1, bv1, Wv2, bv2, out);
}